// Round 9
// baseline (4024.971 us; speedup 1.0000x reference)
//
#include <hip/hip_runtime.h>
#include <cstdint>
#include <cstddef>

// Problem: B=64, T=512, I=128, H=256, 4H=1024, C=3. All fp32 in/out.
typedef _Float16 half2_t __attribute__((ext_vector_type(2)));
typedef _Float16 half8_t __attribute__((ext_vector_type(8)));
typedef float f32x4 __attribute__((ext_vector_type(4)));
typedef unsigned int uint32;

static __device__ __forceinline__ float fdot2(half2_t a, half2_t b, float c) {
    return __builtin_amdgcn_fdot2(a, b, c, false);
}
static __device__ __forceinline__ half2_t h2(uint32 u) {
    return __builtin_bit_cast(half2_t, u);
}
static __device__ __forceinline__ float sigm(float x) {
    return 1.f / (1.f + __expf(-x));
}
static __device__ __forceinline__ float tanh_fast(float x) {
    float ax = fabsf(x);
    float e = __expf(2.f * ax);
    float r = 1.f - 2.f / (e + 1.f);
    return copysignf(r, x);
}

// ---------------------------------------------------------------------------
// prep: W_hh (1024x256 fp32) -> f16 split for the j-split scan.
// WG p owns units u in [p*128,(p+1)*128); its 512 rows indexed by
// tid = g*128 + (u&127), g = row>>8. k-slice s (8 cols) placed:
//   own-k (s in [p*16, p*16+16)): r = s-p*16; r<13 -> WR[p][r][tid] (regs)
//                                 else -> WL[p][r-13][tid] (LDS slices 0..2)
//   peer-k: pr = s-(1-p)*16 -> WL[p][3+pr][tid] (LDS slices 3..18)
// bias = b_ih + b_hh.
// ---------------------------------------------------------------------------
__global__ __launch_bounds__(256) void prep_whh(const float* __restrict__ Whh,
                                                const float* __restrict__ bih,
                                                const float* __restrict__ bhh,
                                                uint4* __restrict__ WR,
                                                uint4* __restrict__ WL,
                                                float* __restrict__ bias) {
    int n = blockIdx.x * 256 + threadIdx.x;  // 0..32767
    if (n < 1024) bias[n] = bih[n] + bhh[n];
    int row = n & 1023;
    int s = n >> 10;  // 0..31
    union { uint4 u; _Float16 h[8]; } cv;
#pragma unroll
    for (int q = 0; q < 8; ++q) cv.h[q] = (_Float16)Whh[row * 256 + s * 8 + q];
    int g = row >> 8, u = row & 255;
    int p = u >> 7, tid = g * 128 + (u & 127);
    int own0 = p * 16;
    if (s >= own0 && s < own0 + 16) {
        int r = s - own0;
        if (r < 13) WR[(p * 13 + r) * 512 + tid] = cv.u;
        else        WL[(p * 19 + (r - 13)) * 512 + tid] = cv.u;
    } else {
        int pr = s - (1 - p) * 16;
        WL[(p * 19 + 3 + pr) * 512 + tid] = cv.u;
    }
}

// f32 -> f16, 4 elements/thread
__global__ __launch_bounds__(256) void cvt_f16(const float* __restrict__ in,
                                               _Float16* __restrict__ out, int n4) {
    int i = blockIdx.x * 256 + threadIdx.x;
    if (i < n4) {
        float4 v = ((const float4*)in)[i];
        union { ushort4 u; _Float16 h[4]; } cv;
        cv.h[0] = (_Float16)v.x; cv.h[1] = (_Float16)v.y;
        cv.h[2] = (_Float16)v.z; cv.h[3] = (_Float16)v.w;
        ((ushort4*)out)[i] = cv.u;
    }
}

// ---------------------------------------------------------------------------
// gemm_mfma: C[M][1024] = A[M][K](f16) * W[1024][K](f16)^T + bias, fp32 out.
// ---------------------------------------------------------------------------
__global__ __launch_bounds__(256) void gemm_mfma(const _Float16* __restrict__ A,
                                                 const _Float16* __restrict__ Bw,
                                                 const float* __restrict__ bias,
                                                 float* __restrict__ Cmat, int K) {
    __shared__ _Float16 As[64][72];
    __shared__ _Float16 Bs[64][72];
    const int tid = threadIdx.x;
    const int wave = tid >> 6, lane = tid & 63;
    const int quad = lane >> 4, l16 = lane & 15;
    const int m0 = blockIdx.x * 64, n0 = blockIdx.y * 64;
    const int sr = tid >> 2;
    const int sc = (tid & 3) * 16;

    f32x4 acc[4] = {};

    for (int k0 = 0; k0 < K; k0 += 64) {
        const uint4 a0v = *(const uint4*)(A + (size_t)(m0 + sr) * K + k0 + sc);
        const uint4 a1v = *(const uint4*)(A + (size_t)(m0 + sr) * K + k0 + sc + 8);
        const uint4 b0v = *(const uint4*)(Bw + (size_t)(n0 + sr) * K + k0 + sc);
        const uint4 b1v = *(const uint4*)(Bw + (size_t)(n0 + sr) * K + k0 + sc + 8);
        __syncthreads();
        *(uint4*)&As[sr][sc] = a0v;
        *(uint4*)&As[sr][sc + 8] = a1v;
        *(uint4*)&Bs[sr][sc] = b0v;
        *(uint4*)&Bs[sr][sc + 8] = b1v;
        __syncthreads();
#pragma unroll
        for (int kc = 0; kc < 64; kc += 32) {
            half8_t af = *(const half8_t*)&As[wave * 16 + l16][kc + quad * 8];
#pragma unroll
            for (int nb = 0; nb < 4; ++nb) {
                half8_t bf = *(const half8_t*)&Bs[nb * 16 + l16][kc + quad * 8];
                acc[nb] = __builtin_amdgcn_mfma_f32_16x16x32_f16(af, bf, acc[nb], 0, 0, 0);
            }
        }
    }
#pragma unroll
    for (int nb = 0; nb < 4; ++nb) {
#pragma unroll
        for (int i = 0; i < 4; ++i) {
            int row = m0 + wave * 16 + quad * 4 + i;
            int col = n0 + nb * 16 + l16;
            Cmat[(size_t)row * 1024 + col] = acc[nb][i] + bias[col];
        }
    }
}

// ---------------------------------------------------------------------------
// lstm_scan v9: j-split (R8 + 2 fixes). 128 WGs x 512 thr; WG (b=blk&63,
// p=blk>=64) owns units [p*128, p*128+128) -> 512 gate rows (thread = row).
// Weights FULLY on-chip: 13 k-slices in 52 VGPRs + 19 slices in 152 KB LDS.
// Cross-WG h exchange (128 f16) via global ring mailbox + monotonic flags.
// FIX 1: history/last-h stores were missing "+ lane" (all 64 lanes hit one
//        address -> h0f/hlast were poison -> absmax 2.5e-2).
// FIX 2: spin uses signed (int)flag < t (monotonic exit; poison negative),
//        flag load ACQUIRE.
// ---------------------------------------------------------------------------
__global__ __attribute__((amdgpu_flat_work_group_size(512, 512),
                          amdgpu_waves_per_eu(2, 2)))
void lstm_scan(const float* __restrict__ gx,
               const uint4* __restrict__ WR,
               const uint4* __restrict__ WL,
               uint32* __restrict__ mb,    // [pair][p][slot][64] dwords
               uint32* __restrict__ flg,   // [pair][p] @ 64B spacing
               _Float16* __restrict__ hout,  // layer0: [b][512][256]; layer1: hlast [b][256]
               int store_all) {
    const int blk = blockIdx.x;
    const int b = blk & 63;
    const int p = blk >> 6;          // 0 or 1
    const int q = 1 - p;
    const int tid = threadIdx.x;     // 0..511: row = g*256 + p*128 + uu
    const int g = tid >> 7;          // 0=i 1=f 2=g 3=o
    const int uu = tid & 127;
    const int wave = tid >> 6, lane = tid & 63;

    __shared__ uint4 wlds[19 * 512];                       // 152 KB
    __shared__ _Float16 hsh[256] __attribute__((aligned(16)));
    __shared__ float act[512];

    // stage LDS weight slices (coalesced)
    const uint4* wl = WL + (size_t)p * 19 * 512;
#pragma unroll
    for (int i = 0; i < 19; ++i) wlds[i * 512 + tid] = wl[i * 512 + tid];

    // persistent register weights: own-k slices 0..12 (52 VGPR)
    const uint4* wr = WR + (size_t)p * 13 * 512;
    uint4 rl[13];
#pragma unroll
    for (int r = 0; r < 13; ++r) rl[r] = wr[r * 512 + tid];

    uint32* mbo = mb + ((b * 2 + p) * 2) * 64;   // own mailbox (2 slots)
    uint32* mbp = mb + ((b * 2 + q) * 2) * 64;   // peer mailbox
    uint32* flgo = flg + (b * 2 + p) * 16;
    uint32* flgp = flg + (b * 2 + q) * 16;

    uint32* hshU = (uint32*)hsh;
    const float* gxb = gx + (size_t)b * 512 * 1024;
    const int row = g * 256 + p * 128 + uu;
    uint32* houtU = (uint32*)hout;

    if (tid < 128) hsh[p * 128 + tid] = (_Float16)0.f;
    float c = 0.f;
    float g_cur = gxb[row];
    __syncthreads();

    const int p16 = p * 16, q16 = q * 16;
    const uint4* hb = (const uint4*)hsh;

    for (int t = 0; t < 512; ++t) {
        float g_nxt = 0.f;
        if (t < 511) g_nxt = gxb[(size_t)(t + 1) * 1024 + row];

        float a = 0.f;
        if (t > 0) {
            uint32 d = 0;
            if (wave == 0) {
                // receiver: spin until peer flag >= t (monotonic; poison<0)
                while ((int)__hip_atomic_load(flgp, __ATOMIC_ACQUIRE,
                                              __HIP_MEMORY_SCOPE_AGENT) < t) {
                    __builtin_amdgcn_s_sleep(1);
                }
                d = __hip_atomic_load(&mbp[((t - 1) & 1) * 64 + lane],
                                      __ATOMIC_RELAXED, __HIP_MEMORY_SCOPE_AGENT);
            }
            // own-k dot while the peer load is in flight
            float ax = 0.f, ay = 0.f;
#pragma unroll
            for (int r = 0; r < 13; ++r) {
                const uint4 hv = hb[p16 + r];
                ax = fdot2(h2(rl[r].x), h2(hv.x), ax);
                ax = fdot2(h2(rl[r].y), h2(hv.y), ax);
                ay = fdot2(h2(rl[r].z), h2(hv.z), ay);
                ay = fdot2(h2(rl[r].w), h2(hv.w), ay);
            }
#pragma unroll
            for (int l = 0; l < 3; ++l) {
                const uint4 wv = wlds[l * 512 + tid];
                const uint4 hv = hb[p16 + 13 + l];
                ax = fdot2(h2(wv.x), h2(hv.x), ax);
                ax = fdot2(h2(wv.y), h2(hv.y), ax);
                ay = fdot2(h2(wv.z), h2(hv.z), ay);
                ay = fdot2(h2(wv.w), h2(hv.w), ay);
            }
            if (wave == 0) hshU[q * 64 + lane] = d;  // install peer h half
            __syncthreads();  // B1: peer h visible
            // peer-k dot
#pragma unroll
            for (int l = 3; l < 19; ++l) {
                const uint4 wv = wlds[l * 512 + tid];
                const uint4 hv = hb[q16 + (l - 3)];
                ax = fdot2(h2(wv.x), h2(hv.x), ax);
                ax = fdot2(h2(wv.y), h2(hv.y), ax);
                ay = fdot2(h2(wv.z), h2(hv.z), ay);
                ay = fdot2(h2(wv.w), h2(hv.w), ay);
            }
            a = ax + ay;
        }

        const float pre = a + g_cur;
        act[tid] = (g == 2) ? tanh_fast(pre) : sigm(pre);
        g_cur = g_nxt;
        __syncthreads();  // B2: acts ready; all h reads of this step retired

        if (tid < 128) {
            const float iv = act[uu], fv = act[128 + uu];
            const float gv = act[256 + uu], ov = act[384 + uu];
            c = fv * c + iv * gv;
            hsh[p * 128 + uu] = (_Float16)(ov * tanh_fast(c));
        }
        __syncthreads();  // B3: new own h in LDS

        if (store_all) {
            if (wave == 2) {  // history store (layer 0), 256 B coalesced
                houtU[((((size_t)b * 512 + t) * 256 + p * 128) >> 1) + lane] =
                    hshU[p * 64 + lane];
            }
        } else if (t == 511 && wave == 2) {
            houtU[((((size_t)b * 256) + p * 128) >> 1) + lane] = hshU[p * 64 + lane];
        }
        if (t < 511 && wave == 7) {  // sender: ship h_t, set flag = t+1
            uint32 d2 = hshU[p * 64 + lane];
            __hip_atomic_store(&mbo[(t & 1) * 64 + lane], d2,
                               __ATOMIC_RELAXED, __HIP_MEMORY_SCOPE_AGENT);
            if (lane == 0) {
                __hip_atomic_store(flgo, (uint32)(t + 1),
                                   __ATOMIC_RELEASE, __HIP_MEMORY_SCOPE_AGENT);
            }
        }
    }
}

// ---------------------------------------------------------------------------
// fc_softmax: logits = hlast[b,:](f16) @ fc_w^T + fc_b, softmax over 3
// ---------------------------------------------------------------------------
__global__ __launch_bounds__(64) void fc_softmax(const _Float16* __restrict__ hlast,
                                                 const float* __restrict__ fcw,
                                                 const float* __restrict__ fcb,
                                                 float* __restrict__ out) {
    const int b = blockIdx.x;
    const int lane = threadIdx.x;
    const _Float16* h = hlast + (size_t)b * 256;
    float p0 = 0.f, p1 = 0.f, p2 = 0.f;
    for (int k = lane; k < 256; k += 64) {
        float hv = (float)h[k];
        p0 += hv * fcw[k];
        p1 += hv * fcw[256 + k];
        p2 += hv * fcw[512 + k];
    }
#pragma unroll
    for (int off = 32; off > 0; off >>= 1) {
        p0 += __shfl_down(p0, off);
        p1 += __shfl_down(p1, off);
        p2 += __shfl_down(p2, off);
    }
    if (lane == 0) {
        float l0 = p0 + fcb[0], l1 = p1 + fcb[1], l2 = p2 + fcb[2];
        float m = fmaxf(l0, fmaxf(l1, l2));
        float e0 = __expf(l0 - m), e1 = __expf(l1 - m), e2 = __expf(l2 - m);
        float s = 1.f / (e0 + e1 + e2);
        out[b * 3 + 0] = e0 * s;
        out[b * 3 + 1] = e1 * s;
        out[b * 3 + 2] = e2 * s;
    }
}

extern "C" void kernel_launch(void* const* d_in, const int* in_sizes, int n_in,
                              void* d_out, int out_size, void* d_ws, size_t ws_size,
                              hipStream_t stream) {
    const float* x    = (const float*)d_in[0];
    const float* Wih0 = (const float*)d_in[1];
    const float* Whh0 = (const float*)d_in[2];
    const float* bih0 = (const float*)d_in[3];
    const float* bhh0 = (const float*)d_in[4];
    const float* Wih1 = (const float*)d_in[5];
    const float* Whh1 = (const float*)d_in[6];
    const float* bih1 = (const float*)d_in[7];
    const float* bhh1 = (const float*)d_in[8];
    const float* fcw  = (const float*)d_in[9];
    const float* fcb  = (const float*)d_in[10];
    float* out = (float*)d_out;

    // workspace layout (~161 MB)
    char* ws = (char*)d_ws;
    float* gx        = (float*)ws;     ws += (size_t)32768 * 1024 * 4;  // 134.2 MB
    _Float16* h0f    = (_Float16*)ws;  ws += (size_t)32768 * 256 * 2;   // 16.8 MB
    _Float16* xh     = (_Float16*)ws;  ws += (size_t)32768 * 128 * 2;   // 8.4 MB
    _Float16* hlast  = (_Float16*)ws;  ws += (size_t)64 * 256 * 2;      // 32 KB
    _Float16* Wih0h  = (_Float16*)ws;  ws += (size_t)1024 * 128 * 2;    // 256 KB
    _Float16* Wih1h  = (_Float16*)ws;  ws += (size_t)1024 * 256 * 2;    // 512 KB
    uint4* WR0       = (uint4*)ws;     ws += (size_t)2 * 13 * 512 * 16; // 208 KB
    uint4* WL0       = (uint4*)ws;     ws += (size_t)2 * 19 * 512 * 16; // 304 KB
    uint4* WR1       = (uint4*)ws;     ws += (size_t)2 * 13 * 512 * 16;
    uint4* WL1       = (uint4*)ws;     ws += (size_t)2 * 19 * 512 * 16;
    uint32* mb0      = (uint32*)ws;    ws += (size_t)64 * 2 * 2 * 64 * 4;  // 128 KB
    uint32* mb1      = (uint32*)ws;    ws += (size_t)64 * 2 * 2 * 64 * 4;  // 128 KB
    uint32* flg0     = (uint32*)ws;    ws += (size_t)64 * 2 * 16 * 4;      // 8 KB
    uint32* flg1     = (uint32*)ws;    ws += (size_t)64 * 2 * 16 * 4;      // 8 KB
    float* bias0     = (float*)ws;     ws += 4096;
    float* bias1     = (float*)ws;     ws += 4096;

    prep_whh<<<128, 256, 0, stream>>>(Whh0, bih0, bhh0, WR0, WL0, bias0);
    prep_whh<<<128, 256, 0, stream>>>(Whh1, bih1, bhh1, WR1, WL1, bias1);
    cvt_f16<<<4096, 256, 0, stream>>>(x, xh, 32768 * 128 / 4);
    cvt_f16<<<128, 256, 0, stream>>>(Wih0, Wih0h, 1024 * 128 / 4);
    cvt_f16<<<256, 256, 0, stream>>>(Wih1, Wih1h, 1024 * 256 / 4);

    // layer 0
    gemm_mfma<<<dim3(512, 16), 256, 0, stream>>>(xh, Wih0h, bias0, gx, 128);
    lstm_scan<<<128, 512, 0, stream>>>(gx, WR0, WL0, mb0, flg0, h0f, 1);

    // layer 1
    gemm_mfma<<<dim3(512, 16), 256, 0, stream>>>(h0f, Wih1h, bias1, gx, 256);
    lstm_scan<<<128, 512, 0, stream>>>(gx, WR1, WL1, mb1, flg1, hlast, 0);

    fc_softmax<<<64, 64, 0, stream>>>(hlast, fcw, fcb, out);
}

// Round 10
// 3451.704 us; speedup vs baseline: 1.1661x; 1.1661x over previous
//
#include <hip/hip_runtime.h>
#include <cstdint>
#include <cstddef>

// Problem: B=64, T=512, I=128, H=256, 4H=1024, C=3. All fp32 in/out.
typedef _Float16 half2_t __attribute__((ext_vector_type(2)));
typedef _Float16 half8_t __attribute__((ext_vector_type(8)));
typedef float f32x4 __attribute__((ext_vector_type(4)));
typedef unsigned int uint32;

static __device__ __forceinline__ float fdot2(half2_t a, half2_t b, float c) {
    return __builtin_amdgcn_fdot2(a, b, c, false);
}
static __device__ __forceinline__ half2_t h2(uint32 u) {
    return __builtin_bit_cast(half2_t, u);
}
static __device__ __forceinline__ float sigm(float x) {
    return 1.f / (1.f + __expf(-x));
}
static __device__ __forceinline__ float tanh_fast(float x) {
    float ax = fabsf(x);
    float e = __expf(2.f * ax);
    float r = 1.f - 2.f / (e + 1.f);
    return copysignf(r, x);
}

// ---------------------------------------------------------------------------
// prep: W_hh (1024x256 fp32) -> f16 split for the j-split scan (as R9).
// ---------------------------------------------------------------------------
__global__ __launch_bounds__(256) void prep_whh(const float* __restrict__ Whh,
                                                const float* __restrict__ bih,
                                                const float* __restrict__ bhh,
                                                uint4* __restrict__ WR,
                                                uint4* __restrict__ WL,
                                                float* __restrict__ bias) {
    int n = blockIdx.x * 256 + threadIdx.x;  // 0..32767
    if (n < 1024) bias[n] = bih[n] + bhh[n];
    int row = n & 1023;
    int s = n >> 10;  // 0..31
    union { uint4 u; _Float16 h[8]; } cv;
#pragma unroll
    for (int q = 0; q < 8; ++q) cv.h[q] = (_Float16)Whh[row * 256 + s * 8 + q];
    int g = row >> 8, u = row & 255;
    int p = u >> 7, tid = g * 128 + (u & 127);
    int own0 = p * 16;
    if (s >= own0 && s < own0 + 16) {
        int r = s - own0;
        if (r < 13) WR[(p * 13 + r) * 512 + tid] = cv.u;
        else        WL[(p * 19 + (r - 13)) * 512 + tid] = cv.u;
    } else {
        int pr = s - (1 - p) * 16;
        WL[(p * 19 + 3 + pr) * 512 + tid] = cv.u;
    }
}

// f32 -> f16, 4 elements/thread
__global__ __launch_bounds__(256) void cvt_f16(const float* __restrict__ in,
                                               _Float16* __restrict__ out, int n4) {
    int i = blockIdx.x * 256 + threadIdx.x;
    if (i < n4) {
        float4 v = ((const float4*)in)[i];
        union { ushort4 u; _Float16 h[4]; } cv;
        cv.h[0] = (_Float16)v.x; cv.h[1] = (_Float16)v.y;
        cv.h[2] = (_Float16)v.z; cv.h[3] = (_Float16)v.w;
        ((ushort4*)out)[i] = cv.u;
    }
}

// ---------------------------------------------------------------------------
// gemm_mfma: C[M][1024] = A[M][K](f16) * W[1024][K](f16)^T + bias, fp32 out.
// ---------------------------------------------------------------------------
__global__ __launch_bounds__(256) void gemm_mfma(const _Float16* __restrict__ A,
                                                 const _Float16* __restrict__ Bw,
                                                 const float* __restrict__ bias,
                                                 float* __restrict__ Cmat, int K) {
    __shared__ _Float16 As[64][72];
    __shared__ _Float16 Bs[64][72];
    const int tid = threadIdx.x;
    const int wave = tid >> 6, lane = tid & 63;
    const int quad = lane >> 4, l16 = lane & 15;
    const int m0 = blockIdx.x * 64, n0 = blockIdx.y * 64;
    const int sr = tid >> 2;
    const int sc = (tid & 3) * 16;

    f32x4 acc[4] = {};

    for (int k0 = 0; k0 < K; k0 += 64) {
        const uint4 a0v = *(const uint4*)(A + (size_t)(m0 + sr) * K + k0 + sc);
        const uint4 a1v = *(const uint4*)(A + (size_t)(m0 + sr) * K + k0 + sc + 8);
        const uint4 b0v = *(const uint4*)(Bw + (size_t)(n0 + sr) * K + k0 + sc);
        const uint4 b1v = *(const uint4*)(Bw + (size_t)(n0 + sr) * K + k0 + sc + 8);
        __syncthreads();
        *(uint4*)&As[sr][sc] = a0v;
        *(uint4*)&As[sr][sc + 8] = a1v;
        *(uint4*)&Bs[sr][sc] = b0v;
        *(uint4*)&Bs[sr][sc + 8] = b1v;
        __syncthreads();
#pragma unroll
        for (int kc = 0; kc < 64; kc += 32) {
            half8_t af = *(const half8_t*)&As[wave * 16 + l16][kc + quad * 8];
#pragma unroll
            for (int nb = 0; nb < 4; ++nb) {
                half8_t bf = *(const half8_t*)&Bs[nb * 16 + l16][kc + quad * 8];
                acc[nb] = __builtin_amdgcn_mfma_f32_16x16x32_f16(af, bf, acc[nb], 0, 0, 0);
            }
        }
    }
#pragma unroll
    for (int nb = 0; nb < 4; ++nb) {
#pragma unroll
        for (int i = 0; i < 4; ++i) {
            int row = m0 + wave * 16 + quad * 4 + i;
            int col = n0 + nb * 16 + l16;
            Cmat[(size_t)row * 1024 + col] = acc[nb][i] + bias[col];
        }
    }
}

// ---------------------------------------------------------------------------
// lstm_scan v10: j-split, rendezvous overhaul.
//  R9's step was 3.9 us: the sender's RELEASE (s_waitcnt vmcnt(0)) drained its
//  own gx HBM prefetch issued at step top -> flag delayed 1-2 us every step.
//  v10: (1) gx prefetch moved to BOTTOM of step (after send), 2-deep pipeline
//       (preload gx[0..2], load gx[t+3] at bottom) -> sender's vmcnt covers
//       only its 64 mailbox L2 stores.
//       (2) sender = wave0 right after B3 (wave-level waitcnt covers all 64
//       lanes' stores); receiver = wave7 (separate wave from sender).
//       (3) poll = RELAXED loads, no s_sleep; single ACQUIRE on exit.
// Weights fully on-chip (52 VGPR + 152 KB LDS), zero weight streaming.
// ---------------------------------------------------------------------------
__global__ __attribute__((amdgpu_flat_work_group_size(512, 512),
                          amdgpu_waves_per_eu(2, 2)))
void lstm_scan(const float* __restrict__ gx,
               const uint4* __restrict__ WR,
               const uint4* __restrict__ WL,
               uint32* __restrict__ mb,    // [pair][p][slot][64] dwords
               uint32* __restrict__ flg,   // [pair][p] @ 64B spacing
               _Float16* __restrict__ hout,  // layer0: [b][512][256]; layer1: hlast [b][256]
               int store_all) {
    const int blk = blockIdx.x;
    const int b = blk & 63;
    const int p = blk >> 6;          // 0 or 1 (pair (b, b+64): same XCD under %8)
    const int q = 1 - p;
    const int tid = threadIdx.x;     // 0..511: row = g*256 + p*128 + uu
    const int g = tid >> 7;          // 0=i 1=f 2=g 3=o
    const int uu = tid & 127;
    const int wave = tid >> 6, lane = tid & 63;

    __shared__ uint4 wlds[19 * 512];                       // 152 KB
    __shared__ _Float16 hsh[256] __attribute__((aligned(16)));
    __shared__ float act[512];

    // stage LDS weight slices (coalesced)
    const uint4* wl = WL + (size_t)p * 19 * 512;
#pragma unroll
    for (int i = 0; i < 19; ++i) wlds[i * 512 + tid] = wl[i * 512 + tid];

    // persistent register weights: own-k slices 0..12 (52 VGPR)
    const uint4* wr = WR + (size_t)p * 13 * 512;
    uint4 rl[13];
#pragma unroll
    for (int r = 0; r < 13; ++r) rl[r] = wr[r * 512 + tid];

    uint32* mbo = mb + ((b * 2 + p) * 2) * 64;   // own mailbox (2 slots)
    uint32* mbp = mb + ((b * 2 + q) * 2) * 64;   // peer mailbox
    uint32* flgo = flg + (b * 2 + p) * 16;
    uint32* flgp = flg + (b * 2 + q) * 16;

    uint32* hshU = (uint32*)hsh;
    const float* gxb = gx + (size_t)b * 512 * 1024;
    const int row = g * 256 + p * 128 + uu;
    uint32* houtU = (uint32*)hout;

    if (tid < 128) hsh[p * 128 + tid] = (_Float16)0.f;
    float c = 0.f;
    // 2-deep gx pipeline: g_cur=gx[0], g_nxt=gx[1], g_nn=gx[2]
    float g_cur = gxb[row];
    float g_nxt = gxb[1024 + row];
    float g_nn  = gxb[2048 + row];
    __syncthreads();

    const int p16 = p * 16, q16 = q * 16;
    const uint4* hb = (const uint4*)hsh;

    for (int t = 0; t < 512; ++t) {
        float a = 0.f;
        if (t > 0) {
            uint32 d = 0;
            if (wave == 7) {
                // receiver: relaxed poll (self-throttled ~200cyc/iter), then
                // one acquire load to synchronize, then the data load (sc1).
                while ((int)__hip_atomic_load(flgp, __ATOMIC_RELAXED,
                                              __HIP_MEMORY_SCOPE_AGENT) < t) {}
                (void)__hip_atomic_load(flgp, __ATOMIC_ACQUIRE,
                                        __HIP_MEMORY_SCOPE_AGENT);
                d = __hip_atomic_load(&mbp[((t - 1) & 1) * 64 + lane],
                                      __ATOMIC_RELAXED, __HIP_MEMORY_SCOPE_AGENT);
            }
            // own-k dot while the peer load is in flight
            float ax = 0.f, ay = 0.f;
#pragma unroll
            for (int r = 0; r < 13; ++r) {
                const uint4 hv = hb[p16 + r];
                ax = fdot2(h2(rl[r].x), h2(hv.x), ax);
                ax = fdot2(h2(rl[r].y), h2(hv.y), ax);
                ay = fdot2(h2(rl[r].z), h2(hv.z), ay);
                ay = fdot2(h2(rl[r].w), h2(hv.w), ay);
            }
#pragma unroll
            for (int l = 0; l < 3; ++l) {
                const uint4 wv = wlds[l * 512 + tid];
                const uint4 hv = hb[p16 + 13 + l];
                ax = fdot2(h2(wv.x), h2(hv.x), ax);
                ax = fdot2(h2(wv.y), h2(hv.y), ax);
                ay = fdot2(h2(wv.z), h2(hv.z), ay);
                ay = fdot2(h2(wv.w), h2(hv.w), ay);
            }
            if (wave == 7) hshU[q * 64 + lane] = d;  // install peer h half
            __syncthreads();  // B1: peer h visible
            // peer-k dot
#pragma unroll
            for (int l = 3; l < 19; ++l) {
                const uint4 wv = wlds[l * 512 + tid];
                const uint4 hv = hb[q16 + (l - 3)];
                ax = fdot2(h2(wv.x), h2(hv.x), ax);
                ax = fdot2(h2(wv.y), h2(hv.y), ax);
                ay = fdot2(h2(wv.z), h2(hv.z), ay);
                ay = fdot2(h2(wv.w), h2(hv.w), ay);
            }
            a = ax + ay;
        }

        const float pre = a + g_cur;
        act[tid] = (g == 2) ? tanh_fast(pre) : sigm(pre);
        __syncthreads();  // B2: acts ready; all h reads of this step retired

        if (tid < 128) {
            const float iv = act[uu], fv = act[128 + uu];
            const float gv = act[256 + uu], ov = act[384 + uu];
            c = fv * c + iv * gv;
            hsh[p * 128 + uu] = (_Float16)(ov * tanh_fast(c));
        }
        __syncthreads();  // B3: new own h in LDS (per-wave vmcnt drained)

        // sender: wave0, right after B3. Its only outstanding vmem is the
        // mailbox store (gx prefetch is issued AFTER, below) -> release fence
        // waits ~200-300 cyc L2 ack, not an HBM load.
        if (t < 511 && wave == 0) {
            uint32 d2 = hshU[p * 64 + lane];
            __hip_atomic_store(&mbo[(t & 1) * 64 + lane], d2,
                               __ATOMIC_RELAXED, __HIP_MEMORY_SCOPE_AGENT);
            if (lane == 0) {
                __hip_atomic_store(flgo, (uint32)(t + 1),
                                   __ATOMIC_RELEASE, __HIP_MEMORY_SCOPE_AGENT);
            }
        }

        if (store_all) {
            if (wave == 2) {  // history store (layer 0), 256 B coalesced
                houtU[((((size_t)b * 512 + t) * 256 + p * 128) >> 1) + lane] =
                    hshU[p * 64 + lane];
            }
        } else if (t == 511 && wave == 2) {
            houtU[((((size_t)b * 256) + p * 128) >> 1) + lane] = hshU[p * 64 + lane];
        }

        // gx pipeline shift + issue (AFTER the send so it never sits in the
        // sender's release drain; 2 steps of slack covers HBM latency)
        g_cur = g_nxt;
        g_nxt = g_nn;
        if (t < 509) g_nn = gxb[(size_t)(t + 3) * 1024 + row];
    }
}

// ---------------------------------------------------------------------------
// fc_softmax: logits = hlast[b,:](f16) @ fc_w^T + fc_b, softmax over 3
// ---------------------------------------------------------------------------
__global__ __launch_bounds__(64) void fc_softmax(const _Float16* __restrict__ hlast,
                                                 const float* __restrict__ fcw,
                                                 const float* __restrict__ fcb,
                                                 float* __restrict__ out) {
    const int b = blockIdx.x;
    const int lane = threadIdx.x;
    const _Float16* h = hlast + (size_t)b * 256;
    float p0 = 0.f, p1 = 0.f, p2 = 0.f;
    for (int k = lane; k < 256; k += 64) {
        float hv = (float)h[k];
        p0 += hv * fcw[k];
        p1 += hv * fcw[256 + k];
        p2 += hv * fcw[512 + k];
    }
#pragma unroll
    for (int off = 32; off > 0; off >>= 1) {
        p0 += __shfl_down(p0, off);
        p1 += __shfl_down(p1, off);
        p2 += __shfl_down(p2, off);
    }
    if (lane == 0) {
        float l0 = p0 + fcb[0], l1 = p1 + fcb[1], l2 = p2 + fcb[2];
        float m = fmaxf(l0, fmaxf(l1, l2));
        float e0 = __expf(l0 - m), e1 = __expf(l1 - m), e2 = __expf(l2 - m);
        float s = 1.f / (e0 + e1 + e2);
        out[b * 3 + 0] = e0 * s;
        out[b * 3 + 1] = e1 * s;
        out[b * 3 + 2] = e2 * s;
    }
}

extern "C" void kernel_launch(void* const* d_in, const int* in_sizes, int n_in,
                              void* d_out, int out_size, void* d_ws, size_t ws_size,
                              hipStream_t stream) {
    const float* x    = (const float*)d_in[0];
    const float* Wih0 = (const float*)d_in[1];
    const float* Whh0 = (const float*)d_in[2];
    const float* bih0 = (const float*)d_in[3];
    const float* bhh0 = (const float*)d_in[4];
    const float* Wih1 = (const float*)d_in[5];
    const float* Whh1 = (const float*)d_in[6];
    const float* bih1 = (const float*)d_in[7];
    const float* bhh1 = (const float*)d_in[8];
    const float* fcw  = (const float*)d_in[9];
    const float* fcb  = (const float*)d_in[10];
    float* out = (float*)d_out;

    // workspace layout (~161 MB)
    char* ws = (char*)d_ws;
    float* gx        = (float*)ws;     ws += (size_t)32768 * 1024 * 4;  // 134.2 MB
    _Float16* h0f    = (_Float16*)ws;  ws += (size_t)32768 * 256 * 2;   // 16.8 MB
    _Float16* xh     = (_Float16*)ws;  ws += (size_t)32768 * 128 * 2;   // 8.4 MB
    _Float16* hlast  = (_Float16*)ws;  ws += (size_t)64 * 256 * 2;      // 32 KB
    _Float16* Wih0h  = (_Float16*)ws;  ws += (size_t)1024 * 128 * 2;    // 256 KB
    _Float16* Wih1h  = (_Float16*)ws;  ws += (size_t)1024 * 256 * 2;    // 512 KB
    uint4* WR0       = (uint4*)ws;     ws += (size_t)2 * 13 * 512 * 16; // 208 KB
    uint4* WL0       = (uint4*)ws;     ws += (size_t)2 * 19 * 512 * 16; // 304 KB
    uint4* WR1       = (uint4*)ws;     ws += (size_t)2 * 13 * 512 * 16;
    uint4* WL1       = (uint4*)ws;     ws += (size_t)2 * 19 * 512 * 16;
    uint32* mb0      = (uint32*)ws;    ws += (size_t)64 * 2 * 2 * 64 * 4;  // 128 KB
    uint32* mb1      = (uint32*)ws;    ws += (size_t)64 * 2 * 2 * 64 * 4;  // 128 KB
    uint32* flg0     = (uint32*)ws;    ws += (size_t)64 * 2 * 16 * 4;      // 8 KB
    uint32* flg1     = (uint32*)ws;    ws += (size_t)64 * 2 * 16 * 4;      // 8 KB
    float* bias0     = (float*)ws;     ws += 4096;
    float* bias1     = (float*)ws;     ws += 4096;

    prep_whh<<<128, 256, 0, stream>>>(Whh0, bih0, bhh0, WR0, WL0, bias0);
    prep_whh<<<128, 256, 0, stream>>>(Whh1, bih1, bhh1, WR1, WL1, bias1);
    cvt_f16<<<4096, 256, 0, stream>>>(x, xh, 32768 * 128 / 4);
    cvt_f16<<<128, 256, 0, stream>>>(Wih0, Wih0h, 1024 * 128 / 4);
    cvt_f16<<<256, 256, 0, stream>>>(Wih1, Wih1h, 1024 * 256 / 4);

    // layer 0
    gemm_mfma<<<dim3(512, 16), 256, 0, stream>>>(xh, Wih0h, bias0, gx, 128);
    lstm_scan<<<128, 512, 0, stream>>>(gx, WR0, WL0, mb0, flg0, h0f, 1);

    // layer 1
    gemm_mfma<<<dim3(512, 16), 256, 0, stream>>>(h0f, Wih1h, bias1, gx, 256);
    lstm_scan<<<128, 512, 0, stream>>>(gx, WR1, WL1, mb1, flg1, hlast, 0);

    fc_softmax<<<64, 64, 0, stream>>>(hlast, fcw, fcb, out);
}

// Round 11
// 2205.087 us; speedup vs baseline: 1.8253x; 1.5653x over previous
//
#include <hip/hip_runtime.h>
#include <cstdint>
#include <cstddef>

// Problem: B=64, T=512, I=128, H=256, 4H=1024, C=3. All fp32 in/out.
typedef _Float16 half2_t __attribute__((ext_vector_type(2)));
typedef _Float16 half8_t __attribute__((ext_vector_type(8)));
typedef float f32x4 __attribute__((ext_vector_type(4)));
typedef unsigned int uint32;

static __device__ __forceinline__ float fdot2(half2_t a, half2_t b, float c) {
    return __builtin_amdgcn_fdot2(a, b, c, false);
}
static __device__ __forceinline__ half2_t h2(uint32 u) {
    return __builtin_bit_cast(half2_t, u);
}
static __device__ __forceinline__ float sigm(float x) {
    return 1.f / (1.f + __expf(-x));
}
static __device__ __forceinline__ float tanh_fast(float x) {
    float ax = fabsf(x);
    float e = __expf(2.f * ax);
    float r = 1.f - 2.f / (e + 1.f);
    return copysignf(r, x);
}

// ---------------------------------------------------------------------------
// prep: W_hh (1024x256 fp32) -> f16, slice-major [s][row] in three regions:
//   s = 0..7   -> WpR (persistent-register part, 8 slices)
//   s = 8..16  -> WpL (LDS part, 9 slices = 144 KB)
//   s = 17..31 -> WpS (streamed part, 15 slices = 240 KB/step)
// bias = b_ih + b_hh.
// ---------------------------------------------------------------------------
__global__ __launch_bounds__(256) void prep_whh(const float* __restrict__ Whh,
                                                const float* __restrict__ bih,
                                                const float* __restrict__ bhh,
                                                uint4* __restrict__ WpR,
                                                uint4* __restrict__ WpL,
                                                uint4* __restrict__ WpS,
                                                float* __restrict__ bias) {
    int n = blockIdx.x * 256 + threadIdx.x;  // 0..32767
    if (n < 1024) bias[n] = bih[n] + bhh[n];
    int row = n & 1023;
    int s = n >> 10;  // 0..31
    union { uint4 u; _Float16 h[8]; } cv;
#pragma unroll
    for (int q = 0; q < 8; ++q) cv.h[q] = (_Float16)Whh[row * 256 + s * 8 + q];
    if (s < 8)       WpR[s * 1024 + row] = cv.u;
    else if (s < 17) WpL[(s - 8) * 1024 + row] = cv.u;
    else             WpS[(s - 17) * 1024 + row] = cv.u;
}

// f32 -> f16, 4 elements/thread
__global__ __launch_bounds__(256) void cvt_f16(const float* __restrict__ in,
                                               _Float16* __restrict__ out, int n4) {
    int i = blockIdx.x * 256 + threadIdx.x;
    if (i < n4) {
        float4 v = ((const float4*)in)[i];
        union { ushort4 u; _Float16 h[4]; } cv;
        cv.h[0] = (_Float16)v.x; cv.h[1] = (_Float16)v.y;
        cv.h[2] = (_Float16)v.z; cv.h[3] = (_Float16)v.w;
        ((ushort4*)out)[i] = cv.u;
    }
}

// ---------------------------------------------------------------------------
// gemm_mfma: C[M][1024] = A[M][K](f16) * W[1024][K](f16)^T + bias, fp32 out.
// ---------------------------------------------------------------------------
__global__ __launch_bounds__(256) void gemm_mfma(const _Float16* __restrict__ A,
                                                 const _Float16* __restrict__ Bw,
                                                 const float* __restrict__ bias,
                                                 float* __restrict__ Cmat, int K) {
    __shared__ _Float16 As[64][72];
    __shared__ _Float16 Bs[64][72];
    const int tid = threadIdx.x;
    const int wave = tid >> 6, lane = tid & 63;
    const int quad = lane >> 4, l16 = lane & 15;
    const int m0 = blockIdx.x * 64, n0 = blockIdx.y * 64;
    const int sr = tid >> 2;
    const int sc = (tid & 3) * 16;

    f32x4 acc[4] = {};

    for (int k0 = 0; k0 < K; k0 += 64) {
        const uint4 a0v = *(const uint4*)(A + (size_t)(m0 + sr) * K + k0 + sc);
        const uint4 a1v = *(const uint4*)(A + (size_t)(m0 + sr) * K + k0 + sc + 8);
        const uint4 b0v = *(const uint4*)(Bw + (size_t)(n0 + sr) * K + k0 + sc);
        const uint4 b1v = *(const uint4*)(Bw + (size_t)(n0 + sr) * K + k0 + sc + 8);
        __syncthreads();
        *(uint4*)&As[sr][sc] = a0v;
        *(uint4*)&As[sr][sc + 8] = a1v;
        *(uint4*)&Bs[sr][sc] = b0v;
        *(uint4*)&Bs[sr][sc + 8] = b1v;
        __syncthreads();
#pragma unroll
        for (int kc = 0; kc < 64; kc += 32) {
            half8_t af = *(const half8_t*)&As[wave * 16 + l16][kc + quad * 8];
#pragma unroll
            for (int nb = 0; nb < 4; ++nb) {
                half8_t bf = *(const half8_t*)&Bs[nb * 16 + l16][kc + quad * 8];
                acc[nb] = __builtin_amdgcn_mfma_f32_16x16x32_f16(af, bf, acc[nb], 0, 0, 0);
            }
        }
    }
#pragma unroll
    for (int nb = 0; nb < 4; ++nb) {
#pragma unroll
        for (int i = 0; i < 4; ++i) {
            int row = m0 + wave * 16 + quad * 4 + i;
            int col = n0 + nb * 16 + l16;
            Cmat[(size_t)row * 1024 + col] = acc[nb][i] + bias[col];
        }
    }
}

// ---------------------------------------------------------------------------
// lstm_scan v11: single WG per batch (cross-WG j-split abandoned: measured
// rendezvous floor 3.4 us/step > single-WG streaming floor 2.0 us/step).
// 64 WGs x 512 thr, waves_per_eu(2,2) -> 128-VGPR grant (proven R5/R9/R10).
// Thread tid owns gate rows tid (i|f) and tid+512 (g|o). Weight placement:
//   s 0..7   : 16 uint4 = 64 VGPRs persistent (R9/R10 proved persistence
//              holds at this thread-count/wpe combo)
//   s 8..16  : 144 KB LDS, staged once
//   s 17..31 : streamed from L2 each step (240 KB/WG/step, slice-major
//              coalesced, 3-deep rolling prefetch) -- down from R6's 384 KB
// 2 barriers/step; h + acts in LDS; hist chunk-flush every 16 steps.
// ---------------------------------------------------------------------------
__global__ __attribute__((amdgpu_flat_work_group_size(512, 512),
                          amdgpu_waves_per_eu(2, 2)))
void lstm_scan(const float* __restrict__ gx,
               const uint4* __restrict__ WpR,
               const uint4* __restrict__ WpL,
               const uint4* __restrict__ WpS,
               _Float16* __restrict__ hout,  // layer0: [b][512][256]; layer1: [b][256]
               int store_all) {
    const int b = blockIdx.x;
    const int tid = threadIdx.x;   // 0..511
    const int j = tid & 255;
    const bool isIG = tid < 256;

    __shared__ uint4 wlds[9 * 1024];  // 144 KB: s = 8..16, [s'][row]
    __shared__ _Float16 hsh[256] __attribute__((aligned(16)));
    __shared__ float exf[256], exo[256];
    __shared__ _Float16 hist[16][256] __attribute__((aligned(16)));

    // stage s=8..16 into LDS (coalesced flat copy)
#pragma unroll
    for (int i = 0; i < 18; ++i) {
        int idx = i * 512 + tid;
        wlds[idx] = WpL[idx];
    }
    // persistent register weights: s = 0..7, rows tid and tid+512 (64 VGPR)
    uint4 rl[8], rh[8];
#pragma unroll
    for (int u = 0; u < 8; ++u) {
        rl[u] = WpR[u * 1024 + tid];
        rh[u] = WpR[u * 1024 + 512 + tid];
    }

    if (isIG) hsh[j] = (_Float16)0.f;
    float c = 0.f;
    const float* gxb = gx + (size_t)b * 512 * 1024;
    float gl = gxb[tid], gh = gxb[512 + tid];  // gx for t=0
    __syncthreads();  // wlds + hsh visible

    const uint4* hb = (const uint4*)hsh;

    for (int t = 0; t < 512; ++t) {
        // prefetch next step's gx (consumed next iteration)
        float gl_n = 0.f, gh_n = 0.f;
        if (t < 511) {
            const float* g4 = gxb + (size_t)(t + 1) * 1024;
            gl_n = g4[tid];
            gh_n = g4[512 + tid];
        }
        // stream preload: slices 17..19 (3-deep, covered by reg+LDS compute)
        uint4 s0[3], s1[3];
#pragma unroll
        for (int i = 0; i < 3; ++i) {
            s0[i] = WpS[i * 1024 + tid];
            s1[i] = WpS[i * 1024 + 512 + tid];
        }

        float a0x = 0.f, a0y = 0.f, a1x = 0.f, a1y = 0.f;

        // register part: slices 0..7
#pragma unroll
        for (int u = 0; u < 8; ++u) {
            const uint4 hv = hb[u];
            a0x = fdot2(h2(rl[u].x), h2(hv.x), a0x);
            a0x = fdot2(h2(rl[u].y), h2(hv.y), a0x);
            a0y = fdot2(h2(rl[u].z), h2(hv.z), a0y);
            a0y = fdot2(h2(rl[u].w), h2(hv.w), a0y);
            a1x = fdot2(h2(rh[u].x), h2(hv.x), a1x);
            a1x = fdot2(h2(rh[u].y), h2(hv.y), a1x);
            a1y = fdot2(h2(rh[u].z), h2(hv.z), a1y);
            a1y = fdot2(h2(rh[u].w), h2(hv.w), a1y);
        }
        // LDS part: slices 8..16
#pragma unroll
        for (int u = 0; u < 9; ++u) {
            const uint4 wl = wlds[u * 1024 + tid];
            const uint4 wh = wlds[u * 1024 + 512 + tid];
            const uint4 hv = hb[8 + u];
            a0x = fdot2(h2(wl.x), h2(hv.x), a0x);
            a0x = fdot2(h2(wl.y), h2(hv.y), a0x);
            a0y = fdot2(h2(wl.z), h2(hv.z), a0y);
            a0y = fdot2(h2(wl.w), h2(hv.w), a0y);
            a1x = fdot2(h2(wh.x), h2(hv.x), a1x);
            a1x = fdot2(h2(wh.y), h2(hv.y), a1x);
            a1y = fdot2(h2(wh.z), h2(hv.z), a1y);
            a1y = fdot2(h2(wh.w), h2(hv.w), a1y);
        }
        // streamed part: slices 17..31, 3-deep rolling prefetch
#pragma unroll
        for (int u = 0; u < 15; ++u) {
            const int r = u % 3;
            const uint4 cl = s0[r], ch = s1[r];
            if (u + 3 < 15) {
                s0[r] = WpS[(u + 3) * 1024 + tid];
                s1[r] = WpS[(u + 3) * 1024 + 512 + tid];
            }
            const uint4 hv = hb[17 + u];
            a0x = fdot2(h2(cl.x), h2(hv.x), a0x);
            a0x = fdot2(h2(cl.y), h2(hv.y), a0x);
            a0y = fdot2(h2(cl.z), h2(hv.z), a0y);
            a0y = fdot2(h2(cl.w), h2(hv.w), a0y);
            a1x = fdot2(h2(ch.x), h2(hv.x), a1x);
            a1x = fdot2(h2(ch.y), h2(hv.y), a1x);
            a1y = fdot2(h2(ch.z), h2(hv.z), a1y);
            a1y = fdot2(h2(ch.w), h2(hv.w), a1y);
        }

        const float plo = a0x + a0y + gl;  // row tid     (i or f)
        const float phi = a1x + a1y + gh;  // row tid+512 (g or o)
        float v0 = 0.f, v1 = 0.f;
        if (isIG) { v0 = sigm(plo); v1 = tanh_fast(phi); }
        else      { exf[j] = sigm(plo); exo[j] = sigm(phi); }
        gl = gl_n; gh = gh_n;
        __syncthreads();  // B1: acts visible; all hsh reads of this step done

        if (isIG) {
            const float fv = exf[j], ov = exo[j];
            c = fv * c + v0 * v1;
            const _Float16 hh = (_Float16)(ov * tanh_fast(c));
            hsh[j] = hh;
            if (store_all) hist[t & 15][j] = hh;
        }
        __syncthreads();  // B2: new h visible

        if (store_all && (t & 15) == 15) {
            // flush 16 steps (8 KB) with all 512 threads (16 B each)
            const uint4 v = ((const uint4*)hist)[tid];
            *(uint4*)(hout + (size_t)b * 512 * 256 + (size_t)(t - 15) * 256 + tid * 8) = v;
        }
    }
    if (!store_all && isIG) {
        hout[(size_t)b * 256 + j] = hsh[j];  // compact last-h for the FC
    }
}

// ---------------------------------------------------------------------------
// fc_softmax: logits = hlast[b,:](f16) @ fc_w^T + fc_b, softmax over 3
// ---------------------------------------------------------------------------
__global__ __launch_bounds__(64) void fc_softmax(const _Float16* __restrict__ hlast,
                                                 const float* __restrict__ fcw,
                                                 const float* __restrict__ fcb,
                                                 float* __restrict__ out) {
    const int b = blockIdx.x;
    const int lane = threadIdx.x;
    const _Float16* h = hlast + (size_t)b * 256;
    float p0 = 0.f, p1 = 0.f, p2 = 0.f;
    for (int k = lane; k < 256; k += 64) {
        float hv = (float)h[k];
        p0 += hv * fcw[k];
        p1 += hv * fcw[256 + k];
        p2 += hv * fcw[512 + k];
    }
#pragma unroll
    for (int off = 32; off > 0; off >>= 1) {
        p0 += __shfl_down(p0, off);
        p1 += __shfl_down(p1, off);
        p2 += __shfl_down(p2, off);
    }
    if (lane == 0) {
        float l0 = p0 + fcb[0], l1 = p1 + fcb[1], l2 = p2 + fcb[2];
        float m = fmaxf(l0, fmaxf(l1, l2));
        float e0 = __expf(l0 - m), e1 = __expf(l1 - m), e2 = __expf(l2 - m);
        float s = 1.f / (e0 + e1 + e2);
        out[b * 3 + 0] = e0 * s;
        out[b * 3 + 1] = e1 * s;
        out[b * 3 + 2] = e2 * s;
    }
}

extern "C" void kernel_launch(void* const* d_in, const int* in_sizes, int n_in,
                              void* d_out, int out_size, void* d_ws, size_t ws_size,
                              hipStream_t stream) {
    const float* x    = (const float*)d_in[0];
    const float* Wih0 = (const float*)d_in[1];
    const float* Whh0 = (const float*)d_in[2];
    const float* bih0 = (const float*)d_in[3];
    const float* bhh0 = (const float*)d_in[4];
    const float* Wih1 = (const float*)d_in[5];
    const float* Whh1 = (const float*)d_in[6];
    const float* bih1 = (const float*)d_in[7];
    const float* bhh1 = (const float*)d_in[8];
    const float* fcw  = (const float*)d_in[9];
    const float* fcb  = (const float*)d_in[10];
    float* out = (float*)d_out;

    // workspace layout (~161 MB)
    char* ws = (char*)d_ws;
    float* gx        = (float*)ws;     ws += (size_t)32768 * 1024 * 4;  // 134.2 MB
    _Float16* h0f    = (_Float16*)ws;  ws += (size_t)32768 * 256 * 2;   // 16.8 MB
    _Float16* xh     = (_Float16*)ws;  ws += (size_t)32768 * 128 * 2;   // 8.4 MB
    _Float16* hlast  = (_Float16*)ws;  ws += (size_t)64 * 256 * 2;      // 32 KB
    _Float16* Wih0h  = (_Float16*)ws;  ws += (size_t)1024 * 128 * 2;    // 256 KB
    _Float16* Wih1h  = (_Float16*)ws;  ws += (size_t)1024 * 256 * 2;    // 512 KB
    uint4* WpR0      = (uint4*)ws;     ws += (size_t)8 * 1024 * 16;     // 128 KB
    uint4* WpL0      = (uint4*)ws;     ws += (size_t)9 * 1024 * 16;     // 144 KB
    uint4* WpS0      = (uint4*)ws;     ws += (size_t)15 * 1024 * 16;    // 240 KB
    uint4* WpR1      = (uint4*)ws;     ws += (size_t)8 * 1024 * 16;
    uint4* WpL1      = (uint4*)ws;     ws += (size_t)9 * 1024 * 16;
    uint4* WpS1      = (uint4*)ws;     ws += (size_t)15 * 1024 * 16;
    float* bias0     = (float*)ws;     ws += 4096;
    float* bias1     = (float*)ws;     ws += 4096;

    prep_whh<<<128, 256, 0, stream>>>(Whh0, bih0, bhh0, WpR0, WpL0, WpS0, bias0);
    prep_whh<<<128, 256, 0, stream>>>(Whh1, bih1, bhh1, WpR1, WpL1, WpS1, bias1);
    cvt_f16<<<4096, 256, 0, stream>>>(x, xh, 32768 * 128 / 4);
    cvt_f16<<<128, 256, 0, stream>>>(Wih0, Wih0h, 1024 * 128 / 4);
    cvt_f16<<<256, 256, 0, stream>>>(Wih1, Wih1h, 1024 * 256 / 4);

    // layer 0
    gemm_mfma<<<dim3(512, 16), 256, 0, stream>>>(xh, Wih0h, bias0, gx, 128);
    lstm_scan<<<64, 512, 0, stream>>>(gx, WpR0, WpL0, WpS0, h0f, 1);

    // layer 1
    gemm_mfma<<<dim3(512, 16), 256, 0, stream>>>(h0f, Wih1h, bias1, gx, 256);
    lstm_scan<<<64, 512, 0, stream>>>(gx, WpR1, WpL1, WpS1, hlast, 0);

    fc_softmax<<<64, 64, 0, stream>>>(hlast, fcw, fcb, out);
}